// Round 6
// baseline (25555.067 us; speedup 1.0000x reference)
//
#include <hip/hip_runtime.h>
#include <hip/hip_cooperative_groups.h>
namespace cg = cooperative_groups;

typedef unsigned short u16;
typedef unsigned int   u32;
typedef _Float16 f16;
typedef f16   f16x8 __attribute__((ext_vector_type(8)));
typedef float f32x4 __attribute__((ext_vector_type(4)));

#define B_  64
#define L_  384
#define CS  512   // SRC_DIM
#define H_  512
#define E_  256
#define NC  250
#define T_  127
#define LPAD 264  // LDS ctx stride in f16 (breaks 16-way bank conflict; 528B row, 16B-aligned)

__device__ __forceinline__ float h2f(u16 u){ f16 h; __builtin_memcpy(&h,&u,2); return (float)h; }
__device__ __forceinline__ u16  f2h(float f){ f16 h=(f16)f; u16 u; __builtin_memcpy(&u,&h,2); return u; }
__device__ __forceinline__ float wredsum_b(float v){   // butterfly: all lanes get the sum
#pragma unroll
  for (int o=32;o>0;o>>=1) v += __shfl_xor(v, o, 64);
  return v;
}
__device__ __forceinline__ float tanh_f(float x){
  x = fminf(fmaxf(x, -15.f), 15.f);
  float e = __expf(2.f*x);
  return (e-1.f)/(e+1.f);
}
__device__ __forceinline__ float sigm_f(float x){
  x = fminf(fmaxf(x, -30.f), 30.f);
  return 1.f/(1.f+__expf(-x));
}

// ---------------- one-time converters ----------------
__global__ __launch_bounds__(256) void k_cvt(const float* __restrict__ in, f16* __restrict__ o, int n){
  int i = blockIdx.x*256 + threadIdx.x;
  if (i < n) o[i] = (f16)in[i];
}
__global__ __launch_bounds__(256) void k_packwg(const float* __restrict__ Wih,
    const float* __restrict__ Whh, f16* __restrict__ Wg){
  int i = blockIdx.x*256 + threadIdx.x;   // over 2048*1280
  if (i < 2048*1280){
    int r = i / 1280, c = i - r*1280;
    float v = (c < 768) ? Wih[(size_t)r*768 + c] : Whh[(size_t)r*512 + (c-768)];
    Wg[i] = (f16)v;
  }
}
// Xg layout: [b][768]: emb at 0..256, h at 256..768
__global__ __launch_bounds__(256) void k_initx(const int* __restrict__ text,
    const float* __restrict__ embt, f16* __restrict__ X0){
  int b = blockIdx.x, col = threadIdx.x;
  int tok = text[b*T_];
  X0[(size_t)b*768 + col] = (f16)embt[(size_t)tok*E_ + col];
}

// ---------------- GEMM1: src_feat = src @ Wi2h^T (f32 in, f16 out), 128x128 tiles
__global__ __launch_bounds__(256) void gemm_srcfeat(
    const float* __restrict__ A, const float* __restrict__ W, u16* __restrict__ Cd,
    int M, int N, int K)
{
  __shared__ float As[8][128+4];
  __shared__ float Ws[8][128+4];
  const int tid = threadIdx.x;
  const int bm = blockIdx.x * 128;
  const int bn = blockIdx.y * 128;
  const int lr = tid >> 1;
  const int lc = (tid & 1) * 4;
  const int ty = tid >> 4, tx = tid & 15;
  float acc[8][8];
#pragma unroll
  for (int i=0;i<8;i++)
#pragma unroll
    for (int j=0;j<8;j++) acc[i][j]=0.f;

  for (int k0=0;k0<K;k0+=8){
    float4 va = *(const float4*)(A + (size_t)(bm+lr)*K + k0 + lc);
    float4 vw = *(const float4*)(W + (size_t)(bn+lr)*K + k0 + lc);
    As[lc+0][lr]=va.x; As[lc+1][lr]=va.y; As[lc+2][lr]=va.z; As[lc+3][lr]=va.w;
    Ws[lc+0][lr]=vw.x; Ws[lc+1][lr]=vw.y; Ws[lc+2][lr]=vw.z; Ws[lc+3][lr]=vw.w;
    __syncthreads();
#pragma unroll
    for (int k=0;k<8;k++){
      float a[8], w[8];
#pragma unroll
      for (int i=0;i<8;i++) a[i]=As[k][ty*8+i];
#pragma unroll
      for (int j=0;j<8;j++) w[j]=Ws[k][tx*8+j];
#pragma unroll
      for (int i=0;i<8;i++)
#pragma unroll
        for (int j=0;j<8;j++) acc[i][j] += a[i]*w[j];
    }
    __syncthreads();
  }
#pragma unroll
  for (int i=0;i<8;i++){
    int m = bm + ty*8 + i;
    u16* cp = Cd + (size_t)m*N + bn + tx*8;
    ushort4 o0, o1;
    o0.x=f2h(acc[i][0]); o0.y=f2h(acc[i][1]); o0.z=f2h(acc[i][2]); o0.w=f2h(acc[i][3]);
    o1.x=f2h(acc[i][4]); o1.y=f2h(acc[i][5]); o1.z=f2h(acc[i][6]); o1.w=f2h(acc[i][7]);
    *(ushort4*)cp = o0;
    *(ushort4*)(cp+4) = o1;
  }
}

// ---------------- GEMM2: probs = hs @ Wgen^T + bgen (A f16, W f32, out f32)
__global__ __launch_bounds__(256) void gemm_probs(
    const u16* __restrict__ A, const float* __restrict__ W, const float* __restrict__ bias,
    float* __restrict__ Cd, int M, int N, int K)
{
  __shared__ float As[16][64+1];
  __shared__ float Ws[16][64+1];
  const int tid = threadIdx.x;
  const int bm = blockIdx.x*64, bn = blockIdx.y*64;
  const int lr = tid>>2;
  const int lc = (tid&3)*4;
  const int ty = tid>>4, tx = tid&15;
  float acc[4][4];
#pragma unroll
  for (int i=0;i<4;i++)
#pragma unroll
    for (int j=0;j<4;j++) acc[i][j]=0.f;

  for (int k0=0;k0<K;k0+=16){
    ushort4 va = *(const ushort4*)(A + (size_t)(bm+lr)*K + k0 + lc);
    As[lc+0][lr]=h2f(va.x); As[lc+1][lr]=h2f(va.y); As[lc+2][lr]=h2f(va.z); As[lc+3][lr]=h2f(va.w);
    int n = bn + lr;
    if (n < N){
      float4 vw = *(const float4*)(W + (size_t)n*K + k0 + lc);
      Ws[lc+0][lr]=vw.x; Ws[lc+1][lr]=vw.y; Ws[lc+2][lr]=vw.z; Ws[lc+3][lr]=vw.w;
    } else {
      Ws[lc+0][lr]=0.f; Ws[lc+1][lr]=0.f; Ws[lc+2][lr]=0.f; Ws[lc+3][lr]=0.f;
    }
    __syncthreads();
#pragma unroll
    for (int k=0;k<16;k++){
      float a[4], w[4];
#pragma unroll
      for (int i=0;i<4;i++) a[i]=As[k][ty*4+i];
#pragma unroll
      for (int j=0;j<4;j++) w[j]=Ws[k][tx*4+j];
#pragma unroll
      for (int i=0;i<4;i++)
#pragma unroll
        for (int j=0;j<4;j++) acc[i][j] += a[i]*w[j];
    }
    __syncthreads();
  }
#pragma unroll
  for (int i=0;i<4;i++){
    int m = bm + ty*4 + i;
#pragma unroll
    for (int j=0;j<4;j++){
      int n = bn + tx*4 + j;
      if (n < N) Cd[(size_t)m*N + n] = acc[i][j] + bias[n];
    }
  }
}

// ---------------- persistent cooperative recurrence: 256 blocks x 512 thr, 2 grid syncs/step
// partial:  [16][64][512] f32  proj K-slice partials (written by phase C, summed in A)
// ctx_part: [256][512] f32, s_part: [256] f32  (written by A, combined in C)
__global__ __launch_bounds__(512) void k_loop(
    const float* __restrict__ src, const int* __restrict__ text,
    const float* __restrict__ embt,
    const f16* __restrict__ WhF, const float* __restrict__ bh2h,
    const float* __restrict__ wsc,
    const f16* __restrict__ WgF, const float* __restrict__ b_ih,
    const float* __restrict__ b_hh,
    const u16* __restrict__ sf, float* __restrict__ cbuf,
    f16* __restrict__ X0, f16* __restrict__ X1, u16* __restrict__ hs,
    float* __restrict__ partial, float* __restrict__ ctx_part,
    float* __restrict__ s_part)
{
  cg::grid_group grid = cg::this_grid();
  __shared__ char smem[56*1024];

  const int tid  = threadIdx.x;
  const int w    = tid >> 6, lane = tid & 63;
  const int quad = lane >> 4, l16 = lane & 15;
  const int blk  = blockIdx.x;

  f16* Xg = X0; f16* Xn = X1;
  for (int t = 0; t < T_; ++t){
    // ================= Phase A: logits + exp + ctx partials =================
    {
      const int b = blk >> 2, q = blk & 3;
      float* shp  = (float*)smem;         // [512] proj
      float* shw  = shp + 512;            // [512] wscore
      float* cacc = shw + 512;            // [8][512] per-wave ctx partials
      float* ssum = cacc + 8*512;         // [8]
      {
        int n = tid;
        float p = bh2h[n];
#pragma unroll
        for (int jj=0; jj<16; jj++) p += partial[(size_t)jj*(64*512) + (size_t)b*512 + n];
        shp[n] = p;
        shw[n] = wsc[n];
      }
      __syncthreads();
      float pr[8], wr8[8];
#pragma unroll
      for (int i=0;i<8;i++){ pr[i]=shp[lane*8+i]; wr8[i]=shw[lane*8+i]; }
      float ctx8[8] = {0,0,0,0,0,0,0,0};
      float se = 0.f;
      for (int li=0; li<12; ++li){
        int l = q*96 + w*12 + li;
        const u16* sp = sf + (((size_t)(b*L_ + l))<<9) + lane*8;
        ushort4 s0=*(const ushort4*)sp, s1=*(const ushort4*)(sp+4);
        float v = tanh_f(h2f(s0.x)+pr[0])*wr8[0] + tanh_f(h2f(s0.y)+pr[1])*wr8[1]
                + tanh_f(h2f(s0.z)+pr[2])*wr8[2] + tanh_f(h2f(s0.w)+pr[3])*wr8[3]
                + tanh_f(h2f(s1.x)+pr[4])*wr8[4] + tanh_f(h2f(s1.y)+pr[5])*wr8[5]
                + tanh_f(h2f(s1.z)+pr[6])*wr8[6] + tanh_f(h2f(s1.w)+pr[7])*wr8[7];
        v = wredsum_b(v);
        float e = __expf(v);   // |logit| small: no max-subtraction needed
        se += e;
        const float* qp = src + (((size_t)(b*L_ + l))<<9) + lane*8;
        float4 r0 = *(const float4*)qp, r1 = *(const float4*)(qp+4);
        ctx8[0]+=e*r0.x; ctx8[1]+=e*r0.y; ctx8[2]+=e*r0.z; ctx8[3]+=e*r0.w;
        ctx8[4]+=e*r1.x; ctx8[5]+=e*r1.y; ctx8[6]+=e*r1.z; ctx8[7]+=e*r1.w;
      }
#pragma unroll
      for (int i=0;i<8;i++) cacc[w*512 + lane*8 + i] = ctx8[i];
      if (lane==0) ssum[w] = se;
      __syncthreads();
      {
        int n = tid;
        float cv = 0.f;
#pragma unroll
        for (int ww=0; ww<8; ww++) cv += cacc[ww*512 + n];
        ctx_part[(size_t)blk*512 + n] = cv;
        if (tid==0){
          float s=0.f;
#pragma unroll
          for (int ww=0; ww<8; ww++) s += ssum[ww];
          s_part[blk] = s;
        }
      }
    }
    grid.sync();
    // ================= Phase C: ctx combine + gates MFMA + cell + proj partials ===========
    if (blk < 16){
      f16*   lctx = (f16*)smem;                       // [64][LPAD=264] -> 33792 B
      float* gbuf = (float*)(smem + 64*LPAD*2);       // [4][64][16] -> 16384 B
      f16*   h_sl = (f16*)(smem + 64*LPAD*2 + 16384); // [64][32] -> 4096 B
      float* invs = (float*)(smem + 64*LPAD*2 + 16384 + 4096); // [64]
      const int wv = w>>2, g = w&3;
      const int j2 = blk*2 + wv;                      // j-tile (16 h) index
      if (tid < 64){
        float s = s_part[tid*4] + s_part[tid*4+1] + s_part[tid*4+2] + s_part[tid*4+3];
        invs[tid] = 1.f/s;
      }
      __syncthreads();
      f32x4 acc[4] = {};
      const f16* bp = WgF + (size_t)(g*512 + j2*16 + l16)*1280 + quad*8;
      // ctx K in two staged halves through LDS
#pragma unroll
      for (int s=0; s<2; s++){
#pragma unroll
        for (int i=0;i<32;i++){
          int o = i*512 + tid;           // 64 b x 256 cols
          int b2 = o >> 8, cl = o & 255;
          int n = s*256 + cl;
          float cv = ctx_part[(size_t)(b2*4+0)*512+n] + ctx_part[(size_t)(b2*4+1)*512+n]
                   + ctx_part[(size_t)(b2*4+2)*512+n] + ctx_part[(size_t)(b2*4+3)*512+n];
          lctx[b2*LPAD + cl] = (f16)(cv * invs[b2]);
        }
        __syncthreads();
        for (int k0=0;k0<256;k0+=32){
          f16x8 bfr = *(const f16x8*)(bp + s*256 + k0);
#pragma unroll
          for (int f=0;f<4;f++){
            f16x8 afr = *(const f16x8*)(lctx + (f*16+l16)*LPAD + k0 + quad*8);
            acc[f] = __builtin_amdgcn_mfma_f32_16x16x32_f16(afr, bfr, acc[f], 0,0,0);
          }
        }
        __syncthreads();
      }
      // emb+h K range from global Xg [64][768]
      for (int k0=512;k0<1280;k0+=32){
        f16x8 bfr = *(const f16x8*)(bp + k0);
#pragma unroll
        for (int f=0;f<4;f++){
          f16x8 afr = *(const f16x8*)(Xg + (size_t)(f*16+l16)*768 + (k0-512) + quad*8);
          acc[f] = __builtin_amdgcn_mfma_f32_16x16x32_f16(afr, bfr, acc[f], 0,0,0);
        }
      }
      // epilogue, one wv-half at a time (gbuf is 16KB)
#pragma unroll
      for (int half=0; half<2; half++){
        if (wv == half){
#pragma unroll
          for (int f=0;f<4;f++)
#pragma unroll
            for (int r=0;r<4;r++)
              gbuf[g*1024 + (f*16+quad*4+r)*16 + l16] = acc[f][r];
        }
        __syncthreads();
#pragma unroll
        for (int i=0;i<2;i++){
          int cidx = tid + i*512;        // 64 b x 16 h
          int b2 = cidx >> 4, hl = cidx & 15;
          int hg = (blk*2+half)*16 + hl;
          float gi = gbuf[0*1024 + b2*16+hl] + b_ih[hg]      + b_hh[hg];
          float gf = gbuf[1*1024 + b2*16+hl] + b_ih[512+hg]  + b_hh[512+hg];
          float gg = gbuf[2*1024 + b2*16+hl] + b_ih[1024+hg] + b_hh[1024+hg];
          float go = gbuf[3*1024 + b2*16+hl] + b_ih[1536+hg] + b_hh[1536+hg];
          float fi=sigm_f(gi), ff=sigm_f(gf), fg=tanh_f(gg), fo=sigm_f(go);
          size_t ci = ((size_t)b2<<9) + hg;
          float cn = ff*cbuf[ci] + fi*fg;
          float hn = fo*tanh_f(cn);
          cbuf[ci] = cn;
          Xn[(size_t)b2*768 + 256 + hg] = (f16)hn;
          hs[(((size_t)(b2*T_ + t))<<9) + hg] = f2h(hn);
          h_sl[b2*32 + half*16 + hl] = (f16)hn;
        }
        __syncthreads();
      }
      // proj(t+1) K-slice partial: partial[blk][b][n] = Wh2h[n, blk*32..+32] @ h_sl
      // wave w: n-tiles w*4..w*4+4, m-tiles 0..4, K=32 -> one mfma per tile
#pragma unroll
      for (int nt4=0; nt4<4; nt4++){
        int nt = w*4 + nt4;
        f16x8 bfr = *(const f16x8*)(WhF + (size_t)(nt*16+l16)*512 + blk*32 + quad*8);
#pragma unroll
        for (int mt=0; mt<4; mt++){
          f16x8 afr = *(const f16x8*)(h_sl + (mt*16+l16)*32 + quad*8);
          f32x4 pacc = {};
          pacc = __builtin_amdgcn_mfma_f32_16x16x32_f16(afr, bfr, pacc, 0,0,0);
#pragma unroll
          for (int r=0;r<4;r++)
            partial[(size_t)blk*(64*512) + (size_t)(mt*16+quad*4+r)*512 + nt*16+l16] = pacc[r];
        }
      }
    } else if (blk == 16 && (t+1) < T_){
#pragma unroll
      for (int i=0;i<32;i++){
        int e = tid + i*512;             // 64 b x 256 cols
        int b2 = e >> 8, col = e & 255;
        int tok = text[b2*T_ + t + 1];
        Xn[(size_t)b2*768 + col] = (f16)embt[(size_t)tok*E_ + col];
      }
    }
    grid.sync();
    f16* tmp = Xg; Xg = Xn; Xn = tmp;
  }
}

extern "C" void kernel_launch(void* const* d_in, const int* in_sizes, int n_in,
                              void* d_out, int out_size, void* d_ws, size_t ws_size,
                              hipStream_t stream)
{
  const float* src   = (const float*)d_in[0];
  const int*   text  = (const int*)d_in[1];
  const float* embt  = (const float*)d_in[2];
  const float* Wi2h  = (const float*)d_in[3];
  const float* Wh2h  = (const float*)d_in[4];
  const float* bh2h  = (const float*)d_in[5];
  const float* wsc   = (const float*)d_in[6];
  const float* W_ih  = (const float*)d_in[7];
  const float* b_ih  = (const float*)d_in[8];
  const float* W_hh  = (const float*)d_in[9];
  const float* b_hh  = (const float*)d_in[10];
  const float* Wgen  = (const float*)d_in[11];
  const float* bgen  = (const float*)d_in[12];
  float* out = (float*)d_out;

  // Workspace layout (~42 MB)
  char* p = (char*)d_ws;
  u16*  sf      = (u16*)p;            p += (size_t)B_*L_*H_*2;      // 25.2 MB
  u16*  hs      = (u16*)p;            p += (size_t)B_*T_*H_*2;      //  8.3 MB
  f16*  WhF     = (f16*)p;            p += (size_t)H_*H_*2;         //  0.5 MB
  f16*  WgF     = (f16*)p;            p += (size_t)2048*1280*2;     //  5.2 MB
  f16*  X0      = (f16*)p;            p += (size_t)B_*768*2;        //  96 KB
  f16*  X1      = (f16*)p;            p += (size_t)B_*768*2;
  float* cbuf   = (float*)p;          p += (size_t)B_*H_*4;         // 128 KB
  float* partial= (float*)p;          p += (size_t)16*64*512*4;     //   2 MB
  float* ctxp   = (float*)p;          p += (size_t)256*512*4;       // 512 KB
  float* s_part = (float*)p;          p += (size_t)256*4;

  hipMemsetAsync(X0,      0, (size_t)B_*768*2, stream);
  hipMemsetAsync(cbuf,    0, (size_t)B_*H_*4, stream);
  hipMemsetAsync(partial, 0, (size_t)16*64*512*4, stream);

  k_cvt   <<<(H_*H_+255)/256, 256, 0, stream>>>(Wh2h, WhF, H_*H_);
  k_packwg<<<(2048*1280+255)/256, 256, 0, stream>>>(W_ih, W_hh, WgF);
  k_initx <<<B_, 256, 0, stream>>>(text, embt, X0);

  dim3 g1(B_*L_/128, H_/128);
  gemm_srcfeat<<<g1, 256, 0, stream>>>(src, Wi2h, sf, B_*L_, H_, CS);

  {
    const u16* sfp = sf;
    u16* hsp = hs;
    void* kargs[] = {
      (void*)&src, (void*)&text, (void*)&embt,
      (void*)&WhF, (void*)&bh2h, (void*)&wsc,
      (void*)&WgF, (void*)&b_ih, (void*)&b_hh,
      (void*)&sfp, (void*)&cbuf, (void*)&X0, (void*)&X1, (void*)&hsp,
      (void*)&partial, (void*)&ctxp, (void*)&s_part
    };
    hipLaunchCooperativeKernel((const void*)k_loop, dim3(256), dim3(512),
                               kargs, 0, stream);
  }

  dim3 g2(B_*T_/64, (NC+63)/64);
  gemm_probs<<<g2, 256, 0, stream>>>(hs, Wgen, bgen, out, B_*T_, NC, H_);
}